// Round 3
// baseline (754.450 us; speedup 1.0000x reference)
//
#include <hip/hip_runtime.h>
#include <math.h>

// GCN forward, gather formulation:
//   CSR build (hist -> scan -> bucket fill), then per layer:
//   GEMM (feature transform) + pull-gather aggregation (no float atomics).
// Layout: H=32 floats/node = 128B row; gather uses 32 lanes/node (lane=col),
// so each edge is ONE coalesced 128B read of hW[src]. Self-loop + bias folded
// into the accumulator init: acc = b[c] + dinv[i]^2 * hW[i,c].

static inline int cdiv(long a, int b) { return (int)((a + (long)b - 1) / b); }

#define CH 1024  // scan chunk per block

__global__ void k_zero_i(int* __restrict__ p, int n) {
  int i = blockIdx.x * 256 + threadIdx.x;
  if (i < n) p[i] = 0;
}

__global__ void k_hist(const int* __restrict__ dst, int* __restrict__ cnt, int E) {
  int e = blockIdx.x * 256 + threadIdx.x;
  if (e < E) atomicAdd(&cnt[dst[e]], 1);
}

// dinv[i] = 1/sqrt(deg), deg = cnt + 1 (self-loop)
__global__ void k_dinv(const int* __restrict__ cnt, float* __restrict__ d, int N) {
  int i = blockIdx.x * 256 + threadIdx.x;
  if (i < N) d[i] = rsqrtf((float)cnt[i] + 1.0f);
}

// exclusive scan of cnt[0..n) into rowptr, per-block totals to bsum
__global__ __launch_bounds__(256) void k_scan1(const int* __restrict__ cnt, int n,
                                               int* __restrict__ outp, int* __restrict__ bsum) {
  __shared__ int tsum[256];
  int base = blockIdx.x * CH;
  int t = threadIdx.x;
  int v[4];
  int s = 0;
#pragma unroll
  for (int k = 0; k < 4; ++k) {
    int idx = base + t * 4 + k;
    v[k] = s;
    s += (idx < n) ? cnt[idx] : 0;
  }
  tsum[t] = s;
  __syncthreads();
  for (int o = 1; o < 256; o <<= 1) {
    int val = (t >= o) ? tsum[t - o] : 0;
    __syncthreads();
    tsum[t] += val;
    __syncthreads();
  }
  int ex = (t == 0) ? 0 : tsum[t - 1];
#pragma unroll
  for (int k = 0; k < 4; ++k) {
    int idx = base + t * 4 + k;
    if (idx < n) outp[idx] = ex + v[k];
  }
  if (t == 255) bsum[blockIdx.x] = tsum[255];
}

// exclusive scan of bsum[0..nb) in-place (nb <= 256)
__global__ void k_scan2(int* __restrict__ bsum, int nb) {
  __shared__ int sm[256];
  int t = threadIdx.x;
  sm[t] = (t < nb) ? bsum[t] : 0;
  __syncthreads();
  for (int o = 1; o < 256; o <<= 1) {
    int val = (t >= o) ? sm[t - o] : 0;
    __syncthreads();
    sm[t] += val;
    __syncthreads();
  }
  if (t < nb) bsum[t] = (t == 0) ? 0 : sm[t - 1];
}

__global__ void k_scan3(int* __restrict__ rowptr, const int* __restrict__ bsumEx,
                        int n, int E) {
  int i = blockIdx.x * 256 + threadIdx.x;
  if (i < n) rowptr[i] += bsumEx[i / CH];
  if (i == 0) rowptr[n] = E;
}

// esrc grouped by dst: pos = rowptr[dst] + cursor[dst]++
__global__ void k_fill(const int* __restrict__ src, const int* __restrict__ dst,
                       const int* __restrict__ rowptr, int* __restrict__ cursor,
                       int* __restrict__ esrc, int E) {
  int e = blockIdx.x * 256 + threadIdx.x;
  if (e >= E) return;
  int d = dst[e];
  int p = rowptr[d] + atomicAdd(&cursor[d], 1);
  esrc[p] = src[e];
}

// hW = x @ W1   (x: [N,128], W1: [128,32])
__global__ __launch_bounds__(256) void k_gemm1(
    const float* __restrict__ x, const float* __restrict__ W1,
    float* __restrict__ hW, int N) {
  __shared__ float w[128 * 32];
  for (int i = threadIdx.x; i < 128 * 32; i += 256) w[i] = W1[i];
  __syncthreads();
  int gid = blockIdx.x * 256 + threadIdx.x;
  int r = gid >> 5, c = gid & 31;
  if (r >= N) return;
  const float4* xr = (const float4*)(x + (size_t)r * 128);
  float acc = 0.f;
#pragma unroll
  for (int k4 = 0; k4 < 32; ++k4) {
    float4 xv = xr[k4];
    acc = fmaf(xv.x, w[(k4 * 4 + 0) * 32 + c], acc);
    acc = fmaf(xv.y, w[(k4 * 4 + 1) * 32 + c], acc);
    acc = fmaf(xv.z, w[(k4 * 4 + 2) * 32 + c], acc);
    acc = fmaf(xv.w, w[(k4 * 4 + 3) * 32 + c], acc);
  }
  hW[gid] = acc;
}

// hW = relu(h) @ W2   (h: [N,32] pre-ReLU, W2: [32,32])
__global__ __launch_bounds__(256) void k_gemm2(
    const float* __restrict__ h, const float* __restrict__ W2,
    float* __restrict__ hW, int N) {
  __shared__ float w[32 * 32];
  for (int i = threadIdx.x; i < 32 * 32; i += 256) w[i] = W2[i];
  __syncthreads();
  int gid = blockIdx.x * 256 + threadIdx.x;
  int r = gid >> 5, c = gid & 31;
  if (r >= N) return;
  const float4* hr = (const float4*)(h + (size_t)r * 32);
  float acc = 0.f;
#pragma unroll
  for (int k4 = 0; k4 < 8; ++k4) {
    float4 v = hr[k4];
    acc = fmaf(fmaxf(v.x, 0.f), w[(k4 * 4 + 0) * 32 + c], acc);
    acc = fmaf(fmaxf(v.y, 0.f), w[(k4 * 4 + 1) * 32 + c], acc);
    acc = fmaf(fmaxf(v.z, 0.f), w[(k4 * 4 + 2) * 32 + c], acc);
    acc = fmaf(fmaxf(v.w, 0.f), w[(k4 * 4 + 3) * 32 + c], acc);
  }
  hW[gid] = acc;
}

// agg[i,c] = b[c] + dinv[i]^2*hW[i,c] + sum_j dinv[i]*dinv[s_j]*hW[s_j,c]
// 32 lanes per node; lane = feature column.
__global__ __launch_bounds__(256) void k_gather(
    const int* __restrict__ esrc, const int* __restrict__ rowptr,
    const float* __restrict__ dinv, const float* __restrict__ hW,
    const float* __restrict__ bias, float* __restrict__ agg, int N) {
  int gid = blockIdx.x * 256 + threadIdx.x;
  int i = gid >> 5, c = gid & 31;
  if (i >= N) return;
  float dv = dinv[i];
  float acc = fmaf(dv * dv, hW[(size_t)i * 32 + c], bias[c]);
  int beg = rowptr[i], end = rowptr[i + 1];
  for (int j = beg; j < end; ++j) {
    int s = esrc[j];                       // wave-broadcast (same addr, 32 lanes)
    float nrm = dv * dinv[s];              // wave-broadcast
    acc = fmaf(nrm, hW[(size_t)s * 32 + c], acc);  // one 128B coalesced req
  }
  agg[(size_t)i * 32 + c] = acc;
}

// scores[1+i] = relu(h[i,:]) . Wh + bh ; scores[0] = cash
__global__ void k_score(const float* __restrict__ h, const float* __restrict__ Wh,
                        const float* __restrict__ bh, const float* __restrict__ cash,
                        float* __restrict__ s, int N) {
  int i = blockIdx.x * 256 + threadIdx.x;
  if (i == 0) s[0] = cash[0];
  if (i < N) {
    const float4* hr = (const float4*)(h + (size_t)i * 32);
    float acc = bh[0];
#pragma unroll
    for (int k4 = 0; k4 < 8; ++k4) {
      float4 v = hr[k4];
      acc = fmaf(fmaxf(v.x, 0.f), Wh[k4 * 4 + 0], acc);
      acc = fmaf(fmaxf(v.y, 0.f), Wh[k4 * 4 + 1], acc);
      acc = fmaf(fmaxf(v.z, 0.f), Wh[k4 * 4 + 2], acc);
      acc = fmaf(fmaxf(v.w, 0.f), Wh[k4 * 4 + 3], acc);
    }
    s[1 + i] = acc;
  }
}

__global__ void k_red_max(const float* __restrict__ s, int n, float* __restrict__ part) {
  float m = -3.4e38f;
  for (int i = blockIdx.x * blockDim.x + threadIdx.x; i < n; i += gridDim.x * blockDim.x)
    m = fmaxf(m, s[i]);
  __shared__ float sm[256];
  sm[threadIdx.x] = m;
  __syncthreads();
  for (int o = 128; o > 0; o >>= 1) {
    if (threadIdx.x < o) sm[threadIdx.x] = fmaxf(sm[threadIdx.x], sm[threadIdx.x + o]);
    __syncthreads();
  }
  if (threadIdx.x == 0) part[blockIdx.x] = sm[0];
}

__global__ void k_red_sumexp(const float* __restrict__ s, int n,
                             const float* __restrict__ mptr, float* __restrict__ part) {
  float m = *mptr;
  float acc = 0.f;
  for (int i = blockIdx.x * blockDim.x + threadIdx.x; i < n; i += gridDim.x * blockDim.x)
    acc += expf(s[i] - m);
  __shared__ float sm[256];
  sm[threadIdx.x] = acc;
  __syncthreads();
  for (int o = 128; o > 0; o >>= 1) {
    if (threadIdx.x < o) sm[threadIdx.x] += sm[threadIdx.x + o];
    __syncthreads();
  }
  if (threadIdx.x == 0) part[blockIdx.x] = sm[0];
}

__global__ void k_red_sum(const float* __restrict__ s, int n, float* __restrict__ outp) {
  float acc = 0.f;
  for (int i = threadIdx.x; i < n; i += blockDim.x) acc += s[i];
  __shared__ float sm[256];
  sm[threadIdx.x] = acc;
  __syncthreads();
  for (int o = 128; o > 0; o >>= 1) {
    if (threadIdx.x < o) sm[threadIdx.x] += sm[threadIdx.x + o];
    __syncthreads();
  }
  if (threadIdx.x == 0) *outp = sm[0];
}

__global__ void k_softmax_out(const float* __restrict__ s, int n,
                              const float* __restrict__ finals, float* __restrict__ out) {
  int i = blockIdx.x * 256 + threadIdx.x;
  if (i < n) out[i] = expf(s[i] - finals[0]) / finals[1];
}

extern "C" void kernel_launch(void* const* d_in, const int* in_sizes, int n_in,
                              void* d_out, int out_size, void* d_ws, size_t ws_size,
                              hipStream_t stream) {
  const float* x    = (const float*)d_in[0];
  const int*   ei   = (const int*)d_in[1];
  const float* W1   = (const float*)d_in[2];
  const float* b1   = (const float*)d_in[3];
  const float* W2   = (const float*)d_in[4];
  const float* b2   = (const float*)d_in[5];
  const float* Wh   = (const float*)d_in[6];
  const float* bh   = (const float*)d_in[7];
  const float* cash = (const float*)d_in[8];

  const int N = in_sizes[0] / 128;
  const int E = in_sizes[1] / 2;
  const int* src = ei;
  const int* dst = ei + E;
  const int NB = cdiv(N, CH);  // scan blocks (<=256 required; 98 here)

  char* p = (char*)d_ws;
  float* dinv   = (float*)p; p += sizeof(float) * N;
  float* hW     = (float*)p; p += sizeof(float) * (size_t)N * 32;
  float* agg    = (float*)p; p += sizeof(float) * (size_t)N * 32;  // reused L1+L2
  float* scores = (float*)p; p += sizeof(float) * (N + 1);
  float* part   = (float*)p; p += sizeof(float) * 256;
  float* finals = (float*)p; p += sizeof(float) * 4;
  int* cnt    = (int*)p; p += sizeof(int) * N;
  int* rowptr = (int*)p; p += sizeof(int) * (N + 1);
  int* cursor = (int*)p; p += sizeof(int) * N;
  int* bsum   = (int*)p; p += sizeof(int) * 256;
  int* esrc   = (int*)p; p += sizeof(int) * (size_t)E;
  float* out = (float*)d_out;
  const int n = N + 1;

  // --- CSR build (shared by both layers) ---
  k_zero_i<<<cdiv(N, 256), 256, 0, stream>>>(cnt, N);
  k_zero_i<<<cdiv(N, 256), 256, 0, stream>>>(cursor, N);
  k_hist<<<cdiv(E, 256), 256, 0, stream>>>(dst, cnt, E);
  k_dinv<<<cdiv(N, 256), 256, 0, stream>>>(cnt, dinv, N);
  k_scan1<<<NB, 256, 0, stream>>>(cnt, N, rowptr, bsum);
  k_scan2<<<1, 256, 0, stream>>>(bsum, NB);
  k_scan3<<<cdiv(N, 256), 256, 0, stream>>>(rowptr, bsum, N, E);
  k_fill<<<cdiv(E, 256), 256, 0, stream>>>(src, dst, rowptr, cursor, esrc, E);

  // --- layer 1 ---
  k_gemm1<<<cdiv((long)N * 32, 256), 256, 0, stream>>>(x, W1, hW, N);
  k_gather<<<cdiv((long)N * 32, 256), 256, 0, stream>>>(esrc, rowptr, dinv, hW, b1, agg, N);

  // --- layer 2 (agg buffer reused: gemm2 reads it, gather overwrites it) ---
  k_gemm2<<<cdiv((long)N * 32, 256), 256, 0, stream>>>(agg, W2, hW, N);
  k_gather<<<cdiv((long)N * 32, 256), 256, 0, stream>>>(esrc, rowptr, dinv, hW, b2, agg, N);

  // --- score + softmax ---
  k_score<<<cdiv(N, 256), 256, 0, stream>>>(agg, Wh, bh, cash, scores, N);
  k_red_max<<<256, 256, 0, stream>>>(scores, n, part);
  k_red_max<<<1, 256, 0, stream>>>(part, 256, finals);
  k_red_sumexp<<<256, 256, 0, stream>>>(scores, n, finals, part);
  k_red_sum<<<1, 256, 0, stream>>>(part, 256, finals + 1);
  k_softmax_out<<<cdiv(n, 256), 256, 0, stream>>>(scores, n, finals, out);
}

// Round 4
// 535.992 us; speedup vs baseline: 1.4076x; 1.4076x over previous
//
#include <hip/hip_runtime.h>
#include <math.h>

// GCN forward, gather formulation:
//   CSR build (hist+arrival-idx -> scan -> atomic-free bucket fill), then per
//   layer: GEMM (feature transform) + pull-gather aggregation (no float atomics).
// Layout: H=32 floats/node = 128B row; gather uses 32 lanes/node (lane=col),
// so each edge is ONE coalesced 128B read of hW[src]. Self-loop + bias folded
// into the accumulator init: acc = b[c] + dinv[i]^2 * hW[i,c].
// k_fill is atomic-free: k_hist records each edge's arrival rank (myidx) so
// fill is pure coalesced-read + fire-and-forget scattered 4B store.

static inline int cdiv(long a, int b) { return (int)((a + (long)b - 1) / b); }

#define CH 1024  // scan chunk per block

__global__ void k_zero_i(int* __restrict__ p, int n) {
  int i = blockIdx.x * 256 + threadIdx.x;
  if (i < n) p[i] = 0;
}

// cnt[d]++ and record this edge's arrival rank (coalesced store)
__global__ void k_hist(const int* __restrict__ dst, int* __restrict__ cnt,
                       int* __restrict__ myidx, int E) {
  int e = blockIdx.x * 256 + threadIdx.x;
  if (e < E) myidx[e] = atomicAdd(&cnt[dst[e]], 1);
}

// dinv[i] = 1/sqrt(deg), deg = cnt + 1 (self-loop)
__global__ void k_dinv(const int* __restrict__ cnt, float* __restrict__ d, int N) {
  int i = blockIdx.x * 256 + threadIdx.x;
  if (i < N) d[i] = rsqrtf((float)cnt[i] + 1.0f);
}

// exclusive scan of cnt[0..n) into rowptr, per-block totals to bsum
__global__ __launch_bounds__(256) void k_scan1(const int* __restrict__ cnt, int n,
                                               int* __restrict__ outp, int* __restrict__ bsum) {
  __shared__ int tsum[256];
  int base = blockIdx.x * CH;
  int t = threadIdx.x;
  int v[4];
  int s = 0;
#pragma unroll
  for (int k = 0; k < 4; ++k) {
    int idx = base + t * 4 + k;
    v[k] = s;
    s += (idx < n) ? cnt[idx] : 0;
  }
  tsum[t] = s;
  __syncthreads();
  for (int o = 1; o < 256; o <<= 1) {
    int val = (t >= o) ? tsum[t - o] : 0;
    __syncthreads();
    tsum[t] += val;
    __syncthreads();
  }
  int ex = (t == 0) ? 0 : tsum[t - 1];
#pragma unroll
  for (int k = 0; k < 4; ++k) {
    int idx = base + t * 4 + k;
    if (idx < n) outp[idx] = ex + v[k];
  }
  if (t == 255) bsum[blockIdx.x] = tsum[255];
}

// exclusive scan of bsum[0..nb) in-place (nb <= 256)
__global__ void k_scan2(int* __restrict__ bsum, int nb) {
  __shared__ int sm[256];
  int t = threadIdx.x;
  sm[t] = (t < nb) ? bsum[t] : 0;
  __syncthreads();
  for (int o = 1; o < 256; o <<= 1) {
    int val = (t >= o) ? sm[t - o] : 0;
    __syncthreads();
    sm[t] += val;
    __syncthreads();
  }
  if (t < nb) bsum[t] = (t == 0) ? 0 : sm[t - 1];
}

__global__ void k_scan3(int* __restrict__ rowptr, const int* __restrict__ bsumEx,
                        int n, int E) {
  int i = blockIdx.x * 256 + threadIdx.x;
  if (i < n) rowptr[i] += bsumEx[i / CH];
  if (i == 0) rowptr[n] = E;
}

// esrc grouped by dst: pos = rowptr[dst] + myidx[e]. Atomic-free scatter.
__global__ void k_fill(const int* __restrict__ src, const int* __restrict__ dst,
                       const int* __restrict__ rowptr, const int* __restrict__ myidx,
                       int* __restrict__ esrc, int E) {
  int e = blockIdx.x * 256 + threadIdx.x;
  if (e >= E) return;
  int d = dst[e];
  esrc[rowptr[d] + myidx[e]] = src[e];
}

// hW = x @ W1   (x: [N,128], W1: [128,32])
__global__ __launch_bounds__(256) void k_gemm1(
    const float* __restrict__ x, const float* __restrict__ W1,
    float* __restrict__ hW, int N) {
  __shared__ float w[128 * 32];
  for (int i = threadIdx.x; i < 128 * 32; i += 256) w[i] = W1[i];
  __syncthreads();
  int gid = blockIdx.x * 256 + threadIdx.x;
  int r = gid >> 5, c = gid & 31;
  if (r >= N) return;
  const float4* xr = (const float4*)(x + (size_t)r * 128);
  float acc = 0.f;
#pragma unroll
  for (int k4 = 0; k4 < 32; ++k4) {
    float4 xv = xr[k4];
    acc = fmaf(xv.x, w[(k4 * 4 + 0) * 32 + c], acc);
    acc = fmaf(xv.y, w[(k4 * 4 + 1) * 32 + c], acc);
    acc = fmaf(xv.z, w[(k4 * 4 + 2) * 32 + c], acc);
    acc = fmaf(xv.w, w[(k4 * 4 + 3) * 32 + c], acc);
  }
  hW[gid] = acc;
}

// hW = relu(h) @ W2   (h: [N,32] pre-ReLU, W2: [32,32])
__global__ __launch_bounds__(256) void k_gemm2(
    const float* __restrict__ h, const float* __restrict__ W2,
    float* __restrict__ hW, int N) {
  __shared__ float w[32 * 32];
  for (int i = threadIdx.x; i < 32 * 32; i += 256) w[i] = W2[i];
  __syncthreads();
  int gid = blockIdx.x * 256 + threadIdx.x;
  int r = gid >> 5, c = gid & 31;
  if (r >= N) return;
  const float4* hr = (const float4*)(h + (size_t)r * 32);
  float acc = 0.f;
#pragma unroll
  for (int k4 = 0; k4 < 8; ++k4) {
    float4 v = hr[k4];
    acc = fmaf(fmaxf(v.x, 0.f), w[(k4 * 4 + 0) * 32 + c], acc);
    acc = fmaf(fmaxf(v.y, 0.f), w[(k4 * 4 + 1) * 32 + c], acc);
    acc = fmaf(fmaxf(v.z, 0.f), w[(k4 * 4 + 2) * 32 + c], acc);
    acc = fmaf(fmaxf(v.w, 0.f), w[(k4 * 4 + 3) * 32 + c], acc);
  }
  hW[gid] = acc;
}

// agg[i,c] = b[c] + dinv[i]^2*hW[i,c] + sum_j dinv[i]*dinv[s_j]*hW[s_j,c]
// 32 lanes per node; lane = feature column. 2-way unrolled edge loop for ILP.
__global__ __launch_bounds__(256) void k_gather(
    const int* __restrict__ esrc, const int* __restrict__ rowptr,
    const float* __restrict__ dinv, const float* __restrict__ hW,
    const float* __restrict__ bias, float* __restrict__ agg, int N) {
  int gid = blockIdx.x * 256 + threadIdx.x;
  int i = gid >> 5, c = gid & 31;
  if (i >= N) return;
  float dv = dinv[i];
  float acc = fmaf(dv * dv, hW[(size_t)i * 32 + c], bias[c]);
  int beg = rowptr[i], end = rowptr[i + 1];
  int j = beg;
  for (; j + 1 < end; j += 2) {
    int s0 = esrc[j];
    int s1 = esrc[j + 1];
    float n0 = dv * dinv[s0];
    float n1 = dv * dinv[s1];
    float v0 = hW[(size_t)s0 * 32 + c];
    float v1 = hW[(size_t)s1 * 32 + c];
    acc = fmaf(n0, v0, acc);
    acc = fmaf(n1, v1, acc);
  }
  if (j < end) {
    int s = esrc[j];
    acc = fmaf(dv * dinv[s], hW[(size_t)s * 32 + c], acc);
  }
  agg[(size_t)i * 32 + c] = acc;
}

// scores[1+i] = relu(h[i,:]) . Wh + bh ; scores[0] = cash
__global__ void k_score(const float* __restrict__ h, const float* __restrict__ Wh,
                        const float* __restrict__ bh, const float* __restrict__ cash,
                        float* __restrict__ s, int N) {
  int i = blockIdx.x * 256 + threadIdx.x;
  if (i == 0) s[0] = cash[0];
  if (i < N) {
    const float4* hr = (const float4*)(h + (size_t)i * 32);
    float acc = bh[0];
#pragma unroll
    for (int k4 = 0; k4 < 8; ++k4) {
      float4 v = hr[k4];
      acc = fmaf(fmaxf(v.x, 0.f), Wh[k4 * 4 + 0], acc);
      acc = fmaf(fmaxf(v.y, 0.f), Wh[k4 * 4 + 1], acc);
      acc = fmaf(fmaxf(v.z, 0.f), Wh[k4 * 4 + 2], acc);
      acc = fmaf(fmaxf(v.w, 0.f), Wh[k4 * 4 + 3], acc);
    }
    s[1 + i] = acc;
  }
}

__global__ void k_red_max(const float* __restrict__ s, int n, float* __restrict__ part) {
  float m = -3.4e38f;
  for (int i = blockIdx.x * blockDim.x + threadIdx.x; i < n; i += gridDim.x * blockDim.x)
    m = fmaxf(m, s[i]);
  __shared__ float sm[256];
  sm[threadIdx.x] = m;
  __syncthreads();
  for (int o = 128; o > 0; o >>= 1) {
    if (threadIdx.x < o) sm[threadIdx.x] = fmaxf(sm[threadIdx.x], sm[threadIdx.x + o]);
    __syncthreads();
  }
  if (threadIdx.x == 0) part[blockIdx.x] = sm[0];
}

__global__ void k_red_sumexp(const float* __restrict__ s, int n,
                             const float* __restrict__ mptr, float* __restrict__ part) {
  float m = *mptr;
  float acc = 0.f;
  for (int i = blockIdx.x * blockDim.x + threadIdx.x; i < n; i += gridDim.x * blockDim.x)
    acc += expf(s[i] - m);
  __shared__ float sm[256];
  sm[threadIdx.x] = acc;
  __syncthreads();
  for (int o = 128; o > 0; o >>= 1) {
    if (threadIdx.x < o) sm[threadIdx.x] += sm[threadIdx.x + o];
    __syncthreads();
  }
  if (threadIdx.x == 0) part[blockIdx.x] = sm[0];
}

__global__ void k_red_sum(const float* __restrict__ s, int n, float* __restrict__ outp) {
  float acc = 0.f;
  for (int i = threadIdx.x; i < n; i += blockDim.x) acc += s[i];
  __shared__ float sm[256];
  sm[threadIdx.x] = acc;
  __syncthreads();
  for (int o = 128; o > 0; o >>= 1) {
    if (threadIdx.x < o) sm[threadIdx.x] += sm[threadIdx.x + o];
    __syncthreads();
  }
  if (threadIdx.x == 0) *outp = sm[0];
}

__global__ void k_softmax_out(const float* __restrict__ s, int n,
                              const float* __restrict__ finals, float* __restrict__ out) {
  int i = blockIdx.x * 256 + threadIdx.x;
  if (i < n) out[i] = expf(s[i] - finals[0]) / finals[1];
}

extern "C" void kernel_launch(void* const* d_in, const int* in_sizes, int n_in,
                              void* d_out, int out_size, void* d_ws, size_t ws_size,
                              hipStream_t stream) {
  const float* x    = (const float*)d_in[0];
  const int*   ei   = (const int*)d_in[1];
  const float* W1   = (const float*)d_in[2];
  const float* b1   = (const float*)d_in[3];
  const float* W2   = (const float*)d_in[4];
  const float* b2   = (const float*)d_in[5];
  const float* Wh   = (const float*)d_in[6];
  const float* bh   = (const float*)d_in[7];
  const float* cash = (const float*)d_in[8];

  const int N = in_sizes[0] / 128;
  const int E = in_sizes[1] / 2;
  const int* src = ei;
  const int* dst = ei + E;
  const int NB = cdiv(N, CH);  // scan blocks (<=256 required; 98 here)

  char* p = (char*)d_ws;
  float* dinv   = (float*)p; p += sizeof(float) * N;
  float* hW     = (float*)p; p += sizeof(float) * (size_t)N * 32;
  float* agg    = (float*)p; p += sizeof(float) * (size_t)N * 32;  // reused L1+L2
  float* scores = (float*)p; p += sizeof(float) * (N + 1);
  float* part   = (float*)p; p += sizeof(float) * 256;
  float* finals = (float*)p; p += sizeof(float) * 4;
  int* cnt    = (int*)p; p += sizeof(int) * N;
  int* rowptr = (int*)p; p += sizeof(int) * (N + 1);
  int* bsum   = (int*)p; p += sizeof(int) * 256;
  int* myidx  = (int*)p; p += sizeof(int) * (size_t)E;
  int* esrc   = (int*)p; p += sizeof(int) * (size_t)E;
  float* out = (float*)d_out;
  const int n = N + 1;

  // --- CSR build (shared by both layers) ---
  k_zero_i<<<cdiv(N, 256), 256, 0, stream>>>(cnt, N);
  k_hist<<<cdiv(E, 256), 256, 0, stream>>>(dst, cnt, myidx, E);
  k_dinv<<<cdiv(N, 256), 256, 0, stream>>>(cnt, dinv, N);
  k_scan1<<<NB, 256, 0, stream>>>(cnt, N, rowptr, bsum);
  k_scan2<<<1, 256, 0, stream>>>(bsum, NB);
  k_scan3<<<cdiv(N, 256), 256, 0, stream>>>(rowptr, bsum, N, E);
  k_fill<<<cdiv(E, 256), 256, 0, stream>>>(src, dst, rowptr, myidx, esrc, E);

  // --- layer 1 ---
  k_gemm1<<<cdiv((long)N * 32, 256), 256, 0, stream>>>(x, W1, hW, N);
  k_gather<<<cdiv((long)N * 32, 256), 256, 0, stream>>>(esrc, rowptr, dinv, hW, b1, agg, N);

  // --- layer 2 (agg buffer reused: gemm2 reads it, gather overwrites it) ---
  k_gemm2<<<cdiv((long)N * 32, 256), 256, 0, stream>>>(agg, W2, hW, N);
  k_gather<<<cdiv((long)N * 32, 256), 256, 0, stream>>>(esrc, rowptr, dinv, hW, b2, agg, N);

  // --- score + softmax ---
  k_score<<<cdiv(N, 256), 256, 0, stream>>>(agg, Wh, bh, cash, scores, N);
  k_red_max<<<256, 256, 0, stream>>>(scores, n, part);
  k_red_max<<<1, 256, 0, stream>>>(part, 256, finals);
  k_red_sumexp<<<256, 256, 0, stream>>>(scores, n, finals, part);
  k_red_sum<<<1, 256, 0, stream>>>(part, 256, finals + 1);
  k_softmax_out<<<cdiv(n, 256), 256, 0, stream>>>(scores, n, finals, out);
}